// Round 13
// baseline (357.068 us; speedup 1.0000x reference)
//
#include <hip/hip_runtime.h>
#include <hip/hip_bf16.h>
#include <hip/hip_cooperative_groups.h>

namespace cg = cooperative_groups;

// z: (8,2048,64) f32 -> N=16384, D=64 ; codebook: (8192,64) f32
// outputs (f32, concat): z_q_st[1048576], vq_loss[1], idx[16384],
//   new_codebook[524288], new_cs[8192], new_ws[524288]
//
// Two launch paths computing IDENTICAL results:
//  A) one cooperative kernel (grid-stride phases + grid.sync), grid sized
//     from the occupancy API (R12's fixed-1024 launch was silently rejected)
//  B) fallback: the R11 4-kernel sequence (known-good, 152 us)

#define NQ 16384
#define KC 8192
#define DD 64
#define NSPLIT 8
#define CSPLIT (KC / NSPLIT)     // 1024 codes per mfma job
#define GROUP 128                // codes staged in LDS per barrier
#define NGROUP (CSPLIT / GROUP)  // 8
#define NTILE (GROUP / 16)       // 8 MFMA c-tiles per staged group
#define IMGH 16384               // halves per group image (32 KB)
#define MJOBS 1024               // mfma jobs (128 qblocks x 8 splits)

#define SC_BLOCKS 256
#define SC_CODES (KC / SC_BLOCKS)  // 32 codes per tail block (path B)
#define TJOBS 1024
#define TC_CODES (KC / TJOBS)      // 8 codes per tail job (path A)

typedef _Float16 half8 __attribute__((ext_vector_type(8)));
typedef _Float16 half4v __attribute__((ext_vector_type(4)));
typedef float f32x4 __attribute__((ext_vector_type(4)));
typedef unsigned int u32;

__device__ __forceinline__ void async_copy16(const _Float16* g, _Float16* l) {
  __builtin_amdgcn_global_load_lds(
      (const __attribute__((address_space(1))) u32*)(const void*)g,
      (__attribute__((address_space(3))) u32*)(void*)l, 16, 0, 0);
}

// ---------------- workspace layout (floats) ----------------
// [0)       nhcn    8192    (-0.5*||c||^2)
// [8192)    epart   32      (ema_cs partial sums)
// [8256)    parts   4096    (loss partials; A uses 1024, B uses 4096)
// [12352)   pmax    131072  (8 x 16384 partial max-u)
// [143424)  pidx    131072  (int)
// [274496)  idx_i   16384   (int)
// [290880)  Cxs     524288  (f16 x 1048576: 64 group images x 32 KB)

// ============ shared phase bodies (device inline) ============

__device__ __forceinline__ void prep_job(int job, int t,
                                         const float* __restrict__ cb,
                                         _Float16* __restrict__ Cxs,
                                         float* __restrict__ nhcn) {
  const int gid = job * 256 + t;
  const int c = gid >> 4;
  const int j4 = gid & 15;
  const f32x4 v = ((const f32x4*)cb)[gid];
  half4v hh, ll;
  float s = 0.f;
#pragma unroll
  for (int e = 0; e < 4; ++e) {
    const float f = v[e];
    const _Float16 h = (_Float16)f;
    hh[e] = h;
    ll[e] = (_Float16)(f - (float)h);
    s = fmaf(f, f, s);
  }
  const int r = c & 127;
  const int tt = r >> 4;
  const int n = r & 15;
  const int q = (j4 >> 1) & 3;
  const int ihalf = j4 & 1;
  const int frh = j4 >> 3;
  const int fs = frh * 4 + q;
  const int nw = n ^ fs;
  _Float16* img = Cxs + (size_t)(c >> 7) * IMGH;
  *(half4v*)(img + ((size_t)((tt * 4 + frh) * 64 + q * 16 + nw)) * 8 +
             ihalf * 4) = hh;
  *(half4v*)(img + ((size_t)((tt * 4 + frh + 2) * 64 + q * 16 + nw)) * 8 +
             ihalf * 4) = ll;
#pragma unroll
  for (int off = 1; off < 16; off <<= 1) s += __shfl_xor(s, off, 64);
  if (j4 == 0) nhcn[c] = -0.5f * s;
}

// One mfma job: 128 queries x 1024 codes. LDS = 32 KB staging buffer.
__device__ __forceinline__ void mfma_job(
    int job, int t, _Float16* Bs, const float* __restrict__ z,
    const _Float16* __restrict__ Cxs, const float* __restrict__ nhcn,
    float* __restrict__ pmax, int* __restrict__ pidx) {
  const int lane = t & 63;
  const int w = t >> 6;
  const int split = job & 7;
  const int Qw = (job >> 3) * 128 + w * 32;
  const int n16 = lane & 15;
  const int quad = lane >> 4;
  const half8* Bs8 = (const half8*)Bs;

  const f32x4* __restrict__ z4 = (const f32x4*)z;
  half8 aH0[2], aH1[2], aL0[2], aL1[2];
#pragma unroll
  for (int qt = 0; qt < 2; ++qt) {
    const size_t row16 = (size_t)(Qw + qt * 16 + n16) * 16;
#pragma unroll
    for (int hf = 0; hf < 2; ++hf) {
      const size_t rb = row16 + hf * 8 + quad * 2;
      const f32x4 va = z4[rb];
      const f32x4 vb = z4[rb + 1];
      half8 H, L;
#pragma unroll
      for (int e = 0; e < 4; ++e) {
        const float fa = va[e], fb = vb[e];
        const _Float16 ha = (_Float16)fa, hb = (_Float16)fb;
        H[e] = ha; H[e + 4] = hb;
        L[e] = (_Float16)(fa - (float)ha);
        L[e + 4] = (_Float16)(fb - (float)hb);
      }
      if (hf == 0) { aH0[qt] = H; aL0[qt] = L; }
      else         { aH1[qt] = H; aL1[qt] = L; }
    }
  }

  float best[2][4];
  int bidx[2][4];
#pragma unroll
  for (int qt = 0; qt < 2; ++qt)
#pragma unroll
    for (int r = 0; r < 4; ++r) {
      best[qt][r] = -3.4e38f;
      bidx[qt][r] = 0;
    }

  for (int g = 0; g < NGROUP; ++g) {
    const int C0 = split * CSPLIT + g * GROUP;
    const _Float16* gimg = Cxs + (size_t)(split * NGROUP + g) * IMGH;
    __syncthreads();
#pragma unroll
    for (int p = 0; p < 8; ++p) {
      const int off = (t + 256 * p) * 8;  // halves
      async_copy16(gimg + off, Bs + off);
    }
    __syncthreads();
#pragma unroll
    for (int tt = 0; tt < NTILE; ++tt) {
      const int base = tt * 4 * 64 + quad * 16;
      const half8 b0 = Bs8[base + (n16 ^ quad)];              // Ch k[0,32)
      const half8 b1 = Bs8[base + 64 + (n16 ^ (4 + quad))];   // Ch k[32,64)
      const half8 b2 = Bs8[base + 128 + (n16 ^ quad)];        // Cl k[0,32)
      const half8 b3 = Bs8[base + 192 + (n16 ^ (4 + quad))];  // Cl k[32,64)
      const int c = C0 + tt * 16 + n16;
      const float nc = nhcn[c];
#pragma unroll
      for (int qt = 0; qt < 2; ++qt) {
        f32x4 acc = {nc, nc, nc, nc};
        acc = __builtin_amdgcn_mfma_f32_16x16x32_f16(aH0[qt], b0, acc, 0, 0, 0);
        acc = __builtin_amdgcn_mfma_f32_16x16x32_f16(aH1[qt], b1, acc, 0, 0, 0);
        acc = __builtin_amdgcn_mfma_f32_16x16x32_f16(aH0[qt], b2, acc, 0, 0, 0);
        acc = __builtin_amdgcn_mfma_f32_16x16x32_f16(aH1[qt], b3, acc, 0, 0, 0);
        acc = __builtin_amdgcn_mfma_f32_16x16x32_f16(aL0[qt], b0, acc, 0, 0, 0);
        acc = __builtin_amdgcn_mfma_f32_16x16x32_f16(aL1[qt], b1, acc, 0, 0, 0);
#pragma unroll
        for (int r = 0; r < 4; ++r) {
          const float u = acc[r];
          if (u > best[qt][r]) { best[qt][r] = u; bidx[qt][r] = c; }
        }
      }
    }
  }
#pragma unroll
  for (int qt = 0; qt < 2; ++qt)
#pragma unroll
    for (int r = 0; r < 4; ++r) {
      float u = best[qt][r];
      int c = bidx[qt][r];
#pragma unroll
      for (int off = 1; off < 16; off <<= 1) {
        const float u2 = __shfl_xor(u, off, 64);
        const int c2 = __shfl_xor(c, off, 64);
        if (u2 > u || (u2 == u && c2 < c)) { u = u2; c = c2; }
      }
      if (n16 == 0) {
        const int q = Qw + qt * 16 + quad * 4 + r;
        pmax[(size_t)split * NQ + q] = u;
        pidx[(size_t)split * NQ + q] = c;
      }
    }
}

// One assign query: merge 8 split partials, gather z_q, write idx; returns
// the wave-reduced sq sum (valid in all lanes).
__device__ __forceinline__ float assign_q(
    int q, int d, const float* __restrict__ z, const float* __restrict__ cb,
    const float* __restrict__ pmax, const int* __restrict__ pidx,
    float* __restrict__ out_zq, float* __restrict__ out_idx,
    int* __restrict__ idx_i) {
  const int s = d & 7;
  float v = pmax[(size_t)s * NQ + q];
  int i = pidx[(size_t)s * NQ + q];
#pragma unroll
  for (int off = 1; off < 8; off <<= 1) {
    const float v2 = __shfl_xor(v, off, 64);
    const int i2 = __shfl_xor(i, off, 64);
    if (v2 > v || (v2 == v && i2 < i)) { v = v2; i = i2; }
  }
  const int k = i;  // all lanes agree
  const float zv = z[(size_t)q * DD + d];
  const float cv = cb[(size_t)k * DD + d];
  out_zq[(size_t)q * DD + d] = cv;  // z + (z_q - z)
  const float diff = zv - cv;
  float sq = diff * diff;
#pragma unroll
  for (int off = 1; off < 64; off <<= 1) sq += __shfl_xor(sq, off, 64);
  if (d == 0) {
    out_idx[q] = (float)k;  // exact in f32 (k < 8192)
    idx_i[q] = k;
  }
  return sq;
}

// Tail gather for NCODES codes starting at k0 (acc: NCODES*64 floats in LDS).
template <int NCODES>
__device__ __forceinline__ void tail_job(
    int k0, int t, float* acc, int* cnt, const float* __restrict__ z,
    const int* __restrict__ idx_i, const float* __restrict__ ema_cs,
    const float* __restrict__ ema_ws, float n, float* __restrict__ out_ncs,
    float* __restrict__ out_ncb, float* __restrict__ out_nws) {
  const int w = t >> 6, lane = t & 63;
  for (int i = t; i < NCODES * 64; i += 256) acc[i] = 0.f;
  if (t < NCODES) cnt[t] = 0;
  __syncthreads();
  const int qbase = w * (NQ / 4);
#pragma unroll 4
  for (int it = 0; it < NQ / 4 / 64; ++it) {  // 64 iterations
    const int q = qbase + it * 64 + lane;
    const int kv = idx_i[q];
    const bool hit = (unsigned)(kv - k0) < (unsigned)NCODES;
    unsigned long long m = __ballot(hit);
    while (m) {
      const int j = __ffsll(m) - 1;
      m &= m - 1;
      const int kj = __shfl(kv, j, 64);
      const int qj = qbase + it * 64 + j;
      const float zvj = z[(size_t)qj * DD + lane];
      atomicAdd(&acc[(kj - k0) * 64 + lane], zvj);
      if (lane == 0) atomicAdd(&cnt[kj - k0], 1);
    }
  }
  __syncthreads();
  for (int i = t; i < NCODES * 64; i += 256) {
    const int kl = i >> 6;
    const int k = k0 + kl;
    const float v = 0.99f * ema_cs[k] + 0.01f * (float)cnt[kl];
    const float smoothed = (v + 1e-5f) / (n + (float)KC * 1e-5f) * n;
    const float nws =
        0.99f * ema_ws[(size_t)k * DD + (i & 63)] + 0.01f * acc[i];
    out_nws[(size_t)k0 * DD + i] = nws;
    out_ncb[(size_t)k0 * DD + i] = nws / smoothed;
  }
  if (t < NCODES)
    out_ncs[k0 + t] = 0.99f * ema_cs[k0 + t] + 0.01f * (float)cnt[t];
}

// ============ Path A: one cooperative kernel, grid-stride phases ============

__global__ __launch_bounds__(256, 2) void k_fused(
    const float* __restrict__ z, const float* __restrict__ cb,
    const float* __restrict__ ema_cs, const float* __restrict__ ema_ws,
    float* __restrict__ zq_out, float* __restrict__ loss_out,
    float* __restrict__ idx_out, float* __restrict__ ncb_out,
    float* __restrict__ ncs_out, float* __restrict__ nws_out,
    _Float16* __restrict__ Cxs, float* __restrict__ nhcn,
    float* __restrict__ epart, float* __restrict__ parts,
    float* __restrict__ pmax, int* __restrict__ pidx,
    int* __restrict__ idx_i) {
  cg::grid_group grid = cg::this_grid();
  __shared__ __align__(16) char ldsraw[32768];
  const int b = blockIdx.x;
  const int G = gridDim.x;
  const int t = threadIdx.x;
  const int w = t >> 6;
  const int lane = t & 63;

  // Phase 1: prep (512 jobs) + ema partials (32 jobs)
  for (int job = b; job < 512; job += G) {
    prep_job(job, t, cb, Cxs, nhcn);
    if (job < 32) {
      float su = ema_cs[job * 256 + t];
#pragma unroll
      for (int off = 1; off < 64; off <<= 1) su += __shfl_xor(su, off, 64);
      float* ss = (float*)ldsraw;
      __syncthreads();
      if (lane == 0) ss[w] = su;
      __syncthreads();
      if (t == 0) epart[job] = ss[0] + ss[1] + ss[2] + ss[3];
    }
  }
  grid.sync();

  // Phase 2: MFMA argmax (1024 jobs)
  for (int job = b; job < MJOBS; job += G)
    mfma_job(job, t, (_Float16*)ldsraw, z, Cxs, nhcn, pmax, pidx);
  grid.sync();

  // Phase 3: assign (1024 jobs x 16 queries)
  for (int job = b; job < 1024; job += G) {
    float sqacc = 0.f;
#pragma unroll
    for (int j = 0; j < 4; ++j)
      sqacc += assign_q(job * 16 + w * 4 + j, lane, z, cb, pmax, pidx, zq_out,
                        idx_out, idx_i);
    float* ss = (float*)ldsraw;
    __syncthreads();
    if (lane == 0) ss[w] = sqacc;
    __syncthreads();
    if (t == 0) parts[job] = ss[0] + ss[1] + ss[2] + ss[3];
  }
  grid.sync();

  // Phase 4: tail (1024 jobs x 8 codes); block 0 then reduces loss
  float esum = 0.f;
#pragma unroll
  for (int e = 0; e < 32; ++e) esum += epart[e];
  const float n = 0.99f * esum + 0.01f * 16384.0f;
  float* acc = (float*)ldsraw;
  int* cnt = (int*)(ldsraw + TC_CODES * 64 * 4);
  for (int job = b; job < TJOBS; job += G) {
    __syncthreads();
    tail_job<TC_CODES>(job * TC_CODES, t, acc, cnt, z, idx_i, ema_cs, ema_ws,
                       n, ncs_out, ncb_out, nws_out);
  }
  if (b == 0) {
    __syncthreads();
    float s = 0.f;
    for (int i = t; i < 1024; i += 256) s += parts[i];
#pragma unroll
    for (int off = 1; off < 64; off <<= 1) s += __shfl_xor(s, off, 64);
    if (lane == 0) acc[w] = s;
    __syncthreads();
    if (t == 0)
      *loss_out = 1.25f * (acc[0] + acc[1] + acc[2] + acc[3]) *
                  (1.0f / 1048576.0f);
  }
}

// ============ Path B: R11 4-kernel fallback (known-good) ============

__global__ __launch_bounds__(256) void k_prep(
    const float* __restrict__ cb, const float* __restrict__ ema_cs,
    _Float16* __restrict__ Cxs, float* __restrict__ nhcn,
    float* __restrict__ epart) {
  const int t = threadIdx.x;
  prep_job(blockIdx.x, t, cb, Cxs, nhcn);
  if (blockIdx.x < 32) {
    float su = ema_cs[blockIdx.x * 256 + t];
#pragma unroll
    for (int off = 1; off < 64; off <<= 1) su += __shfl_xor(su, off, 64);
    __shared__ float ss[4];
    if ((t & 63) == 0) ss[t >> 6] = su;
    __syncthreads();
    if (t == 0) epart[blockIdx.x] = ss[0] + ss[1] + ss[2] + ss[3];
  }
}

__global__ __launch_bounds__(256, 4) void k_mfma(
    const float* __restrict__ z, const _Float16* __restrict__ Cxs,
    const float* __restrict__ nhcn, float* __restrict__ pmax,
    int* __restrict__ pidx) {
  __shared__ __align__(16) _Float16 Bs[IMGH];
  mfma_job(blockIdx.x, threadIdx.x, Bs, z, Cxs, nhcn, pmax, pidx);
}

__global__ __launch_bounds__(256) void k_assign(
    const float* __restrict__ z, const float* __restrict__ cb,
    const float* __restrict__ pmax, const int* __restrict__ pidx,
    float* __restrict__ out_zq, float* __restrict__ out_idx,
    int* __restrict__ idx_i, float* __restrict__ parts) {
  const int t = threadIdx.x;
  const float sq = assign_q(blockIdx.x * 4 + (t >> 6), t & 63, z, cb, pmax,
                            pidx, out_zq, out_idx, idx_i);
  __shared__ float ss[4];
  if ((t & 63) == 0) ss[t >> 6] = sq;
  __syncthreads();
  if (t == 0) parts[blockIdx.x] = ss[0] + ss[1] + ss[2] + ss[3];
}

__global__ __launch_bounds__(256) void k_tail(
    const float* __restrict__ z, const int* __restrict__ idx_i,
    const float* __restrict__ ema_cs, const float* __restrict__ ema_ws,
    const float* __restrict__ epart, const float* __restrict__ parts,
    float* __restrict__ out_ncs, float* __restrict__ out_ncb,
    float* __restrict__ out_nws, float* __restrict__ out_loss) {
  __shared__ float acc[SC_CODES * 64];  // 8 KB
  __shared__ int cnt[SC_CODES];
  const int t = threadIdx.x;
  float esum = 0.f;
#pragma unroll
  for (int e = 0; e < 32; ++e) esum += epart[e];
  const float n = 0.99f * esum + 0.01f * 16384.0f;
  tail_job<SC_CODES>(blockIdx.x * SC_CODES, t, acc, cnt, z, idx_i, ema_cs,
                     ema_ws, n, out_ncs, out_ncb, out_nws);
  if (blockIdx.x == 0) {
    __syncthreads();
    float s = 0.f;
    for (int i = t; i < 4096; i += 256) s += parts[i];
#pragma unroll
    for (int off = 1; off < 64; off <<= 1) s += __shfl_xor(s, off, 64);
    if ((t & 63) == 0) acc[t >> 6] = s;
    __syncthreads();
    if (t == 0)
      *out_loss = 1.25f * (acc[0] + acc[1] + acc[2] + acc[3]) *
                  (1.0f / 1048576.0f);
  }
}

extern "C" void kernel_launch(void* const* d_in, const int* in_sizes, int n_in,
                              void* d_out, int out_size, void* d_ws,
                              size_t ws_size, hipStream_t stream) {
  const float* z = (const float*)d_in[0];
  const float* cb = (const float*)d_in[1];
  const float* ema_cs = (const float*)d_in[2];
  const float* ema_ws = (const float*)d_in[3];

  float* out = (float*)d_out;
  float* zq_out = out;              // 1048576
  float* loss_out = out + 1048576;  // 1
  float* idx_out = out + 1048577;   // 16384
  float* ncb_out = out + 1064961;   // 524288
  float* ncs_out = out + 1589249;   // 8192
  float* nws_out = out + 1597441;   // 524288

  float* ws = (float*)d_ws;
  float* nhcn = ws;                          // 8192
  float* epart = ws + 8192;                  // 32
  float* parts = ws + 8256;                  // 4096
  float* pmax = ws + 12352;                  // 131072
  int* pidx = (int*)(ws + 143424);           // 131072
  int* idx_i = (int*)(ws + 274496);          // 16384
  _Float16* Cxs = (_Float16*)(ws + 290880);  // 1048576 halves (2 MB)

  // Path A: cooperative fused kernel, grid sized from the occupancy API.
  int occ = 0;
  hipError_t oe = hipOccupancyMaxActiveBlocksPerMultiprocessor(
      &occ, (const void*)k_fused, 256, 0);
  int G = (oe == hipSuccess) ? occ * 256 : 0;
  if (G > 1024) G = 1024;
  bool coop_done = false;
  if (G >= 8) {
    void* args[] = {&z,       &cb,      &ema_cs,  &ema_ws, &zq_out, &loss_out,
                    &idx_out, &ncb_out, &ncs_out, &nws_out, &Cxs,   &nhcn,
                    &epart,   &parts,   &pmax,    &pidx,    &idx_i};
    hipError_t le = hipLaunchCooperativeKernel((const void*)k_fused, dim3(G),
                                               dim3(256), args, 0, stream);
    coop_done = (le == hipSuccess);
  }

  if (!coop_done) {
    // Path B: R11 sequence (known-good).
    k_prep<<<KC * 16 / 256, 256, 0, stream>>>(cb, ema_cs, Cxs, nhcn, epart);
    k_mfma<<<dim3(MJOBS), 256, 0, stream>>>(z, Cxs, nhcn, pmax, pidx);
    k_assign<<<NQ / 4, 256, 0, stream>>>(z, cb, pmax, pidx, zq_out, idx_out,
                                         idx_i, parts);
    k_tail<<<SC_BLOCKS, 256, 0, stream>>>(z, idx_i, ema_cs, ema_ws, epart,
                                          parts, ncs_out, ncb_out, nws_out,
                                          loss_out);
  }
}

// Round 14
// 152.109 us; speedup vs baseline: 2.3474x; 2.3474x over previous
//
#include <hip/hip_runtime.h>
#include <hip/hip_bf16.h>

// z: (8,2048,64) f32 -> N=16384, D=64 ; codebook: (8192,64) f32
// outputs (f32, concat): z_q_st[1048576], vq_loss[1], idx[16384],
//   new_codebook[524288], new_cs[8192], new_ws[524288]
//
// 3-kernel pipeline (no cooperative launch -- R13 showed grid.sync is a
// 433 us disaster here):
//  k_prep: swizzled f16-split codebook image (Cxs), nhcn, ema partials,
//          qmax/loss zero-init
//  k_mfma: f16-split MFMA argmax; per-query result folded via atomicMax on
//          a sortable u64 pack (u mapped monotonically | 0xFFFFFFFF - c) --
//          exactly reproduces (max u, tie -> smaller c)
//  k_post: blocks 0..255 = q-side (zq gather, idx, loss atomicAdd/block);
//          blocks 256..511 = k-side (ballot-gather dw/cs from qmax low
//          words, EMA/normalize outputs). Both depend only on qmax.

#define NQ 16384
#define KC 8192
#define DD 64
#define NSPLIT 8
#define CSPLIT (KC / NSPLIT)     // 1024 codes per mfma job
#define GROUP 128                // codes staged in LDS per barrier
#define NGROUP (CSPLIT / GROUP)  // 8
#define NTILE (GROUP / 16)       // 8 MFMA c-tiles per staged group
#define IMGH 16384               // halves per group image (32 KB)
#define MJOBS 1024               // 128 qblocks x 8 splits

#define AQ_BLOCKS 256            // k_post q-side blocks (64 queries each)
#define TL_BLOCKS 256            // k_post k-side blocks (32 codes each)
#define TL_CODES (KC / TL_BLOCKS)

typedef _Float16 half8 __attribute__((ext_vector_type(8)));
typedef _Float16 half4v __attribute__((ext_vector_type(4)));
typedef float f32x4 __attribute__((ext_vector_type(4)));
typedef unsigned int u32;
typedef unsigned long long u64;

__device__ __forceinline__ void async_copy16(const _Float16* g, _Float16* l) {
  __builtin_amdgcn_global_load_lds(
      (const __attribute__((address_space(1))) u32*)(const void*)g,
      (__attribute__((address_space(3))) u32*)(void*)l, 16, 0, 0);
}

// Sortable pack: higher u wins; equal u -> smaller c wins.
__device__ __forceinline__ u64 pack_uc(float u, int c) {
  u32 ub = __float_as_uint(u);
  ub = (ub & 0x80000000u) ? ~ub : (ub | 0x80000000u);  // monotone f32->u32
  return ((u64)ub << 32) | (u64)(0xFFFFFFFFu - (u32)c);
}

// ---------------- workspace layout (floats) ----------------
// [0)      nhcn   8192   (-0.5*||c||^2)
// [8192)   epart  32     (ema_cs partial sums)
// [8224)   qmax   32768  (u64[16384], 8B-aligned: 8224*4 = 32896 % 8 == 0)
// [40992)  Cxs    524288 (f16 x 1048576: 64 group images x 32 KB)

__global__ __launch_bounds__(256) void k_prep(
    const float* __restrict__ cb, const float* __restrict__ ema_cs,
    _Float16* __restrict__ Cxs, float* __restrict__ nhcn,
    float* __restrict__ epart, u64* __restrict__ qmax,
    float* __restrict__ loss_out) {
  const int b = blockIdx.x;
  const int t = threadIdx.x;
  const int gid = b * 256 + t;
  const int c = gid >> 4;
  const int j4 = gid & 15;

  const f32x4 v = ((const f32x4*)cb)[gid];
  half4v hh, ll;
  float s = 0.f;
#pragma unroll
  for (int e = 0; e < 4; ++e) {
    const float f = v[e];
    const _Float16 h = (_Float16)f;
    hh[e] = h;
    ll[e] = (_Float16)(f - (float)h);
    s = fmaf(f, f, s);
  }
  const int r = c & 127;
  const int tt = r >> 4;
  const int n = r & 15;
  const int q = (j4 >> 1) & 3;
  const int ihalf = j4 & 1;
  const int frh = j4 >> 3;
  const int fs = frh * 4 + q;
  const int nw = n ^ fs;
  _Float16* img = Cxs + (size_t)(c >> 7) * IMGH;
  *(half4v*)(img + ((size_t)((tt * 4 + frh) * 64 + q * 16 + nw)) * 8 +
             ihalf * 4) = hh;
  *(half4v*)(img + ((size_t)((tt * 4 + frh + 2) * 64 + q * 16 + nw)) * 8 +
             ihalf * 4) = ll;
#pragma unroll
  for (int off = 1; off < 16; off <<= 1) s += __shfl_xor(s, off, 64);
  if (j4 == 0) nhcn[c] = -0.5f * s;

  if (t < 32) qmax[b * 32 + t] = 0ull;  // any packed value > 0
  if (b == 0 && t == 0) *loss_out = 0.f;

  if (b < 32) {
    float su = ema_cs[b * 256 + t];
#pragma unroll
    for (int off = 1; off < 64; off <<= 1) su += __shfl_xor(su, off, 64);
    __shared__ float ss[4];
    if ((t & 63) == 0) ss[t >> 6] = su;
    __syncthreads();
    if (t == 0) epart[b] = ss[0] + ss[1] + ss[2] + ss[3];
  }
}

// MFMA argmax (R11 body). Wave = 32 queries, job = 1024 codes. Result per
// query folded into qmax via atomicMax (2 updates/address across splits).
__global__ __launch_bounds__(256, 4) void k_mfma(
    const float* __restrict__ z, const _Float16* __restrict__ Cxs,
    const float* __restrict__ nhcn, u64* __restrict__ qmax) {
  __shared__ __align__(16) _Float16 Bs[IMGH];  // 32 KB
  const int t = threadIdx.x;
  const int lane = t & 63;
  const int w = t >> 6;
  const int split = blockIdx.x & 7;
  const int Qw = (blockIdx.x >> 3) * 128 + w * 32;
  const int n16 = lane & 15;
  const int quad = lane >> 4;
  const half8* Bs8 = (const half8*)Bs;

  const f32x4* __restrict__ z4 = (const f32x4*)z;
  half8 aH0[2], aH1[2], aL0[2], aL1[2];
#pragma unroll
  for (int qt = 0; qt < 2; ++qt) {
    const size_t row16 = (size_t)(Qw + qt * 16 + n16) * 16;
#pragma unroll
    for (int hf = 0; hf < 2; ++hf) {
      const size_t rb = row16 + hf * 8 + quad * 2;
      const f32x4 va = z4[rb];
      const f32x4 vb = z4[rb + 1];
      half8 H, L;
#pragma unroll
      for (int e = 0; e < 4; ++e) {
        const float fa = va[e], fb = vb[e];
        const _Float16 ha = (_Float16)fa, hb = (_Float16)fb;
        H[e] = ha; H[e + 4] = hb;
        L[e] = (_Float16)(fa - (float)ha);
        L[e + 4] = (_Float16)(fb - (float)hb);
      }
      if (hf == 0) { aH0[qt] = H; aL0[qt] = L; }
      else         { aH1[qt] = H; aL1[qt] = L; }
    }
  }

  float best[2][4];
  int bidx[2][4];
#pragma unroll
  for (int qt = 0; qt < 2; ++qt)
#pragma unroll
    for (int r = 0; r < 4; ++r) {
      best[qt][r] = -3.4e38f;
      bidx[qt][r] = 0;
    }

  for (int g = 0; g < NGROUP; ++g) {
    const int C0 = split * CSPLIT + g * GROUP;
    const _Float16* gimg = Cxs + (size_t)(split * NGROUP + g) * IMGH;
    __syncthreads();
#pragma unroll
    for (int p = 0; p < 8; ++p) {
      const int off = (t + 256 * p) * 8;  // halves
      async_copy16(gimg + off, Bs + off);
    }
    __syncthreads();
#pragma unroll
    for (int tt = 0; tt < NTILE; ++tt) {
      const int base = tt * 4 * 64 + quad * 16;
      const half8 b0 = Bs8[base + (n16 ^ quad)];              // Ch k[0,32)
      const half8 b1 = Bs8[base + 64 + (n16 ^ (4 + quad))];   // Ch k[32,64)
      const half8 b2 = Bs8[base + 128 + (n16 ^ quad)];        // Cl k[0,32)
      const half8 b3 = Bs8[base + 192 + (n16 ^ (4 + quad))];  // Cl k[32,64)
      const int c = C0 + tt * 16 + n16;
      const float nc = nhcn[c];
#pragma unroll
      for (int qt = 0; qt < 2; ++qt) {
        f32x4 acc = {nc, nc, nc, nc};
        acc = __builtin_amdgcn_mfma_f32_16x16x32_f16(aH0[qt], b0, acc, 0, 0, 0);
        acc = __builtin_amdgcn_mfma_f32_16x16x32_f16(aH1[qt], b1, acc, 0, 0, 0);
        acc = __builtin_amdgcn_mfma_f32_16x16x32_f16(aH0[qt], b2, acc, 0, 0, 0);
        acc = __builtin_amdgcn_mfma_f32_16x16x32_f16(aH1[qt], b3, acc, 0, 0, 0);
        acc = __builtin_amdgcn_mfma_f32_16x16x32_f16(aL0[qt], b0, acc, 0, 0, 0);
        acc = __builtin_amdgcn_mfma_f32_16x16x32_f16(aL1[qt], b1, acc, 0, 0, 0);
#pragma unroll
        for (int r = 0; r < 4; ++r) {
          const float u = acc[r];
          if (u > best[qt][r]) { best[qt][r] = u; bidx[qt][r] = c; }
        }
      }
    }
  }
#pragma unroll
  for (int qt = 0; qt < 2; ++qt)
#pragma unroll
    for (int r = 0; r < 4; ++r) {
      float u = best[qt][r];
      int c = bidx[qt][r];
#pragma unroll
      for (int off = 1; off < 16; off <<= 1) {
        const float u2 = __shfl_xor(u, off, 64);
        const int c2 = __shfl_xor(c, off, 64);
        if (u2 > u || (u2 == u && c2 < c)) { u = u2; c = c2; }
      }
      if (n16 == 0) {
        const int q = Qw + qt * 16 + quad * 4 + r;
        atomicMax(&qmax[q], pack_uc(u, c));
      }
    }
}

// k_post: q-side blocks [0,256) + k-side blocks [256,512). Both read only
// qmax low words (c = 0xFFFFFFFF - low32).
__global__ __launch_bounds__(256) void k_post(
    const float* __restrict__ z, const float* __restrict__ cb,
    const float* __restrict__ ema_cs, const float* __restrict__ ema_ws,
    const u32* __restrict__ qlow, const float* __restrict__ epart,
    float* __restrict__ zq_out, float* __restrict__ idx_out,
    float* __restrict__ ncb_out, float* __restrict__ ncs_out,
    float* __restrict__ nws_out, float* __restrict__ loss_out) {
  __shared__ float acc[TL_CODES * 64];  // 8 KB (k-side) / scratch (q-side)
  __shared__ int cnt[TL_CODES];
  const int b = blockIdx.x;
  const int t = threadIdx.x;
  const int w = t >> 6;
  const int lane = t & 63;

  if (b < AQ_BLOCKS) {
    // ---- q-side: 64 queries per block, 16 per wave ----
    float sqacc = 0.f;
    const int qbase = b * 64 + w * 16;
#pragma unroll 4
    for (int j = 0; j < 16; ++j) {
      const int q = qbase + j;
      const int k = (int)(0xFFFFFFFFu - qlow[2 * q]);  // wave-uniform
      const float zv = z[(size_t)q * DD + lane];
      const float cv = cb[(size_t)k * DD + lane];
      zq_out[(size_t)q * DD + lane] = cv;  // z + (z_q - z)
      const float diff = zv - cv;
      sqacc = fmaf(diff, diff, sqacc);
      if (lane == 0) idx_out[q] = (float)k;  // exact in f32 (k < 8192)
    }
#pragma unroll
    for (int off = 1; off < 64; off <<= 1) sqacc += __shfl_xor(sqacc, off, 64);
    if (lane == 0) acc[w] = sqacc;
    __syncthreads();
    if (t == 0)
      atomicAdd(loss_out,
                1.25f * (acc[0] + acc[1] + acc[2] + acc[3]) *
                    (1.0f / 1048576.0f));
  } else {
    // ---- k-side: 32 codes per block ----
    const int k0 = (b - AQ_BLOCKS) * TL_CODES;
    for (int i = t; i < TL_CODES * 64; i += 256) acc[i] = 0.f;
    if (t < TL_CODES) cnt[t] = 0;
    __syncthreads();

    const int qbase = w * (NQ / 4);
#pragma unroll 4
    for (int it = 0; it < NQ / 4 / 64; ++it) {  // 64 iterations
      const int q = qbase + it * 64 + lane;
      const int kv = (int)(0xFFFFFFFFu - qlow[2 * q]);
      const bool hit = (unsigned)(kv - k0) < (unsigned)TL_CODES;
      unsigned long long m = __ballot(hit);
      while (m) {
        const int j = __ffsll(m) - 1;
        m &= m - 1;
        const int kj = __shfl(kv, j, 64);
        const int qj = qbase + it * 64 + j;
        const float zvj = z[(size_t)qj * DD + lane];
        atomicAdd(&acc[(kj - k0) * 64 + lane], zvj);
        if (lane == 0) atomicAdd(&cnt[kj - k0], 1);
      }
    }
    __syncthreads();

    // n = 0.99*sum(ema_cs) + 0.01*NQ  (sum(counts) == NQ exactly)
    float esum = 0.f;
#pragma unroll
    for (int e = 0; e < 32; ++e) esum += epart[e];
    const float n = 0.99f * esum + 0.01f * 16384.0f;

    for (int i = t; i < TL_CODES * 64; i += 256) {
      const int kl = i >> 6;
      const int k = k0 + kl;
      const float v = 0.99f * ema_cs[k] + 0.01f * (float)cnt[kl];
      const float smoothed = (v + 1e-5f) / (n + (float)KC * 1e-5f) * n;
      const float nws =
          0.99f * ema_ws[(size_t)k * DD + (i & 63)] + 0.01f * acc[i];
      nws_out[(size_t)k0 * DD + i] = nws;
      ncb_out[(size_t)k0 * DD + i] = nws / smoothed;
    }
    if (t < TL_CODES)
      ncs_out[k0 + t] = 0.99f * ema_cs[k0 + t] + 0.01f * (float)cnt[t];
  }
}

extern "C" void kernel_launch(void* const* d_in, const int* in_sizes, int n_in,
                              void* d_out, int out_size, void* d_ws,
                              size_t ws_size, hipStream_t stream) {
  const float* z = (const float*)d_in[0];
  const float* cb = (const float*)d_in[1];
  const float* ema_cs = (const float*)d_in[2];
  const float* ema_ws = (const float*)d_in[3];

  float* out = (float*)d_out;
  float* zq_out = out;              // 1048576
  float* loss_out = out + 1048576;  // 1
  float* idx_out = out + 1048577;   // 16384
  float* ncb_out = out + 1064961;   // 524288
  float* ncs_out = out + 1589249;   // 8192
  float* nws_out = out + 1597441;   // 524288

  float* ws = (float*)d_ws;
  float* nhcn = ws;                         // 8192
  float* epart = ws + 8192;                 // 32
  u64* qmax = (u64*)(ws + 8224);            // 16384 x u64 (8B aligned)
  _Float16* Cxs = (_Float16*)(ws + 40992);  // 1048576 halves (2 MB)

  k_prep<<<KC * 16 / 256, 256, 0, stream>>>(cb, ema_cs, Cxs, nhcn, epart,
                                            qmax, loss_out);
  k_mfma<<<MJOBS, 256, 0, stream>>>(z, Cxs, nhcn, qmax);
  k_post<<<AQ_BLOCKS + TL_BLOCKS, 256, 0, stream>>>(
      z, cb, ema_cs, ema_ws, (const u32*)qmax, epart, zq_out, idx_out,
      ncb_out, ncs_out, nws_out, loss_out);
}